// Round 4
// baseline (491.143 us; speedup 1.0000x reference)
//
#include <hip/hip_runtime.h>

static constexpr int cT = 1024;   // tokens
static constexpr int cH = 1024;   // hidden
static constexpr int cI = 2816;   // intermediate
static constexpr int cE = 16;     // experts
static constexpr int cK = 4;      // top-k

typedef __attribute__((ext_vector_type(8))) short bf16x8;
typedef __attribute__((ext_vector_type(4))) float f32x4;
typedef __attribute__((ext_vector_type(2))) unsigned uint2v;
typedef __attribute__((ext_vector_type(4))) unsigned uint4v;

__device__ __forceinline__ unsigned f2bf(float f) {
  unsigned u = __float_as_uint(f);
  return (u + 0x7FFFu + ((u >> 16) & 1u)) >> 16;   // RNE f32->bf16
}
__device__ __forceinline__ unsigned pack2(float lo, float hi) {
  return f2bf(lo) | (f2bf(hi) << 16);
}

// ------------------------------------------------------------- x -> bf16 ----
__global__ __launch_bounds__(256) void xcast_kernel(
    const float* __restrict__ x, unsigned short* __restrict__ xb) {
  const int i = blockIdx.x * 256 + threadIdx.x;
  const float4* xv = (const float4*)x;
  const float4 a = xv[i * 2], b = xv[i * 2 + 1];
  uint4v o;
  o.x = pack2(a.x, a.y); o.y = pack2(a.z, a.w);
  o.z = pack2(b.x, b.y); o.w = pack2(b.z, b.w);
  ((uint4v*)xb)[i] = o;
}

// ---------------------------------------------------------------- router ----
__global__ __launch_bounds__(64) void router_kernel(
    const float* __restrict__ x, const float* __restrict__ Wg,
    int* __restrict__ topk_id, float* __restrict__ topk_w,
    int* __restrict__ counts) {
  const int t = blockIdx.x;
  const int l = threadIdx.x;

  float xa[16];
#pragma unroll
  for (int i = 0; i < 16; ++i) xa[i] = x[(size_t)t * cH + l + 64 * i];

  float lg[16];
#pragma unroll
  for (int e = 0; e < 16; ++e) {
    float s = 0.f;
#pragma unroll
    for (int i = 0; i < 16; ++i) s += xa[i] * Wg[(size_t)e * cH + l + 64 * i];
#pragma unroll
    for (int d = 1; d < 64; d <<= 1) s += __shfl_xor(s, d);
    lg[e] = s;
  }

  if (l == 0) {
    int ids[4]; float vals[4];
    unsigned taken = 0;
#pragma unroll
    for (int j = 0; j < 4; ++j) {
      float m = -1e30f; int mi = 0;
#pragma unroll
      for (int e = 0; e < 16; ++e) {
        bool better = !((taken >> e) & 1u) && lg[e] > m;
        if (better) { m = lg[e]; mi = e; }
      }
      taken |= 1u << mi; ids[j] = mi; vals[j] = m;
    }
    const float mx = vals[0];
    float s = 0.f;
#pragma unroll
    for (int j = 0; j < 4; ++j) { vals[j] = __expf(vals[j] - mx); s += vals[j]; }
    const float inv = 1.f / s;
#pragma unroll
    for (int j = 0; j < 4; ++j) {
      topk_id[t * 4 + j] = ids[j];
      topk_w[t * 4 + j] = vals[j] * inv;
      atomicAdd(&counts[ids[j]], 1);
    }
  }
}

__global__ void scan_kernel(const int* __restrict__ counts,
                            int* __restrict__ offsets) {
  if (threadIdx.x == 0 && blockIdx.x == 0) {
    int acc = 0;
    for (int e = 0; e < cE; ++e) { offsets[e] = acc; acc += counts[e]; }
    offsets[cE] = acc;
  }
}

__global__ __launch_bounds__(256) void scatter_kernel(
    const int* __restrict__ topk_id, const int* __restrict__ offsets,
    int* __restrict__ cursor, int* __restrict__ pair_token,
    int* __restrict__ pair_pos) {
  const int i = blockIdx.x * 256 + threadIdx.x;   // 0..4095
  const int t = i >> 2;
  const int e = topk_id[i];
  const int pos = offsets[e] + atomicAdd(&cursor[e], 1);
  pair_token[pos] = t;
  pair_pos[i] = pos;
}

// act tiled layout: element (p, c) at (p>>4)*45056 + (c>>3)*128 + (p&15)*8 + (c&7)
// -> down's A-fragment reads are 16B/lane, 256B-contiguous per 16-lane group.

// ---------------------------------------------------------------- gate+up ---
// Block = (64-col strip, 128-row chunk, expert). Depth-2 register prefetch of
// weights; b128 swizzled LDS: column n, k-block b stored at
//   n*36 + 4*((b + 2*((n>>2)&3)) & 7)    (conflict-free b128 write AND read)
__global__ __launch_bounds__(256, 3) void gateup_kernel(
    const unsigned short* __restrict__ xb, const float* __restrict__ gw,
    const float* __restrict__ uw, const int* __restrict__ offsets,
    const int* __restrict__ pair_token, unsigned short* __restrict__ actT) {
  const int e = blockIdx.y;
  const int off = offsets[e];
  const int n_e = offsets[e + 1] - off;
  const int strip = blockIdx.x / 3;
  const int c0 = (blockIdx.x % 3) * 128;
  if (c0 >= n_e) return;
  const int nb = strip * 64;
  const int tid = threadIdx.x, l = tid & 63, w = tid >> 6;
  const int q = l & 15, h16 = l >> 4;
  const int hrd = 2 * ((q >> 2) & 3);          // read-side swizzle term

  __shared__ unsigned sB[2][2][2304];          // [buf][mat][swizzled]
  __shared__ int tokl[128];

  // staging: mat = tid>>7; 8 rows x float4 per thread
  const int mat = tid >> 7, tt = tid & 127, rg = tt >> 4, cg = tt & 15;
  const int hwr = 2 * (cg & 3);                // write-side swizzle term
  const float* wsrc = (mat ? uw : gw) + (size_t)e * cH * cI + nb + cg * 4;

#define GU_LDSET(S, KT)                                                       \
  _Pragma("unroll")                                                           \
  for (int j = 0; j < 8; ++j)                                                 \
    S[j] = *(const float4*)(wsrc + (size_t)((KT) * 64 + rg * 8 + j) * cI);

#define GU_PACK(BUF, S)                                                       \
  _Pragma("unroll")                                                           \
  for (int i = 0; i < 4; ++i) {                                               \
    uint4v P;                                                                 \
    P.x = pack2(S[0][i], S[1][i]); P.y = pack2(S[2][i], S[3][i]);             \
    P.z = pack2(S[4][i], S[5][i]); P.w = pack2(S[6][i], S[7][i]);             \
    *(uint4v*)&sB[BUF][mat][(4 * cg + i) * 36 + 4 * ((rg + hwr) & 7)] = P;    \
  }

#define GU_TILE(KT, CUR, SC, SN)                                              \
  {                                                                           \
    if ((KT) + 2 < 16) { GU_LDSET(SC, (KT) + 2) }                             \
    _Pragma("unroll")                                                         \
    for (int ks = 0; ks < 2; ++ks) {                                          \
      const bf16x8 a0 = *(const bf16x8*)(ap0 + (KT) * 64 + ks * 32);          \
      const bf16x8 a1 = *(const bf16x8*)(ap1 + (KT) * 64 + ks * 32);          \
      _Pragma("unroll")                                                       \
      for (int ni = 0; ni < 4; ++ni) {                                        \
        const int ba = (q + 16 * ni) * 36 + 4 * ((h16 + 4 * ks + hrd) & 7);   \
        const bf16x8 bg = *(const bf16x8*)&sB[CUR][0][ba];                    \
        const bf16x8 bu = *(const bf16x8*)&sB[CUR][1][ba];                    \
        ag0[ni] = __builtin_amdgcn_mfma_f32_16x16x32_bf16(a0, bg, ag0[ni], 0, 0, 0); \
        ag1[ni] = __builtin_amdgcn_mfma_f32_16x16x32_bf16(a1, bg, ag1[ni], 0, 0, 0); \
        au0[ni] = __builtin_amdgcn_mfma_f32_16x16x32_bf16(a0, bu, au0[ni], 0, 0, 0); \
        au1[ni] = __builtin_amdgcn_mfma_f32_16x16x32_bf16(a1, bu, au1[ni], 0, 0, 0); \
      }                                                                       \
    }                                                                         \
    if ((KT) + 1 < 16) { GU_PACK(1 - (CUR), SN) __syncthreads(); }            \
  }

  for (int m0 = c0; m0 < n_e; m0 += 384) {
    if (tid < 128) tokl[tid] = pair_token[off + min(m0 + tid, n_e - 1)];
    __syncthreads();
    const int rows = min(128, n_e - m0);

    const unsigned short* ap0 =
        xb + (size_t)tokl[min(w * 32 + q, rows - 1)] * cH + h16 * 8;
    const unsigned short* ap1 =
        xb + (size_t)tokl[min(w * 32 + 16 + q, rows - 1)] * cH + h16 * 8;

    f32x4 ag0[4], ag1[4], au0[4], au1[4];
#pragma unroll
    for (int ni = 0; ni < 4; ++ni) {
      ag0[ni] = (f32x4){0.f, 0.f, 0.f, 0.f}; ag1[ni] = (f32x4){0.f, 0.f, 0.f, 0.f};
      au0[ni] = (f32x4){0.f, 0.f, 0.f, 0.f}; au1[ni] = (f32x4){0.f, 0.f, 0.f, 0.f};
    }

    float4 s0[8], s1[8];
    GU_LDSET(s0, 0)
    GU_LDSET(s1, 1)
    GU_PACK(0, s0)
    __syncthreads();

    for (int kt = 0; kt < 16; kt += 2) {
      GU_TILE(kt, 0, s0, s1)
      GU_TILE(kt + 1, 1, s1, s0)
    }

    // epilogue: silu(g)*u -> bf16 actT (tiled layout)
#define GU_EPI(MI, AGV, AUV)                                                  \
  _Pragma("unroll")                                                           \
  for (int j = 0; j < 4; ++j) {                                               \
    const int er = m0 + w * 32 + (MI) * 16 + h16 * 4 + j;                     \
    if (er < n_e) {                                                           \
      const int p = off + er;                                                 \
      const size_t pb = (size_t)(p >> 4) * 45056 + (p & 15) * 8 +             \
                        (size_t)(nb >> 3) * 128 + (q & 7);                    \
      _Pragma("unroll")                                                       \
      for (int ni = 0; ni < 4; ++ni) {                                        \
        const float g = AGV[ni][j], u = AUV[ni][j];                           \
        const float v = (g / (1.f + __expf(-g))) * u;                         \
        actT[pb + (size_t)(ni * 2 + (q >> 3)) * 128] = (unsigned short)f2bf(v); \
      }                                                                       \
    }                                                                         \
  }
    GU_EPI(0, ag0, au0)
    GU_EPI(1, ag1, au1)
  }
#undef GU_LDSET
#undef GU_PACK
#undef GU_TILE
#undef GU_EPI
}

// ------------------------------------------------------------------ down ----
__global__ __launch_bounds__(256, 4) void down_kernel(
    const unsigned short* __restrict__ actT, const float* __restrict__ dw,
    const int* __restrict__ offsets, float* __restrict__ yp) {
  const int e = blockIdx.y;
  const int off = offsets[e];
  const int n_e = offsets[e + 1] - off;
  const int strip = blockIdx.x / 3;
  const int c0 = (blockIdx.x % 3) * 128;
  if (c0 >= n_e) return;
  const int nb = strip * 64;
  const int tid = threadIdx.x, l = tid & 63, w = tid >> 6;
  const int q = l & 15, h16 = l >> 4;
  const int hrd = 2 * ((q >> 2) & 3);
  constexpr int NT = cI / 64;                  // 44

  __shared__ unsigned sB[2][2304];

  // staging: 8 rows x float2 per thread
  const int rg = tid >> 5, cg = (tid >> 1) & 15, half = tid & 1;
  const int hwr = 2 * (cg & 3);
  const float* dsrc = dw + (size_t)e * cI * cH + nb + cg * 4 + half * 2;

#define DN_LDSET(S, KT)                                                       \
  _Pragma("unroll")                                                           \
  for (int j = 0; j < 8; ++j)                                                 \
    S[j] = *(const float2*)(dsrc + (size_t)((KT) * 64 + rg * 8 + j) * cH);

#define DN_PACK(BUF, S)                                                       \
  _Pragma("unroll")                                                           \
  for (int i = 0; i < 2; ++i) {                                               \
    uint4v P;                                                                 \
    const float* Sf = (const float*)S;                                        \
    P.x = pack2(Sf[0 * 2 + i], Sf[1 * 2 + i]);                                \
    P.y = pack2(Sf[2 * 2 + i], Sf[3 * 2 + i]);                                \
    P.z = pack2(Sf[4 * 2 + i], Sf[5 * 2 + i]);                                \
    P.w = pack2(Sf[6 * 2 + i], Sf[7 * 2 + i]);                                \
    *(uint4v*)&sB[BUF][(4 * cg + 2 * half + i) * 36 + 4 * ((rg + hwr) & 7)] = P; \
  }

#define DN_TILE(KT, CUR, SC, SN)                                              \
  {                                                                           \
    if ((KT) + 2 < NT) { DN_LDSET(SC, (KT) + 2) }                             \
    _Pragma("unroll")                                                         \
    for (int ks = 0; ks < 2; ++ks) {                                          \
      const bf16x8 a0 = *(const bf16x8*)(actT + b0 + (size_t)((KT) * 8 + h16 + 4 * ks) * 128); \
      const bf16x8 a1 = *(const bf16x8*)(actT + b1 + (size_t)((KT) * 8 + h16 + 4 * ks) * 128); \
      _Pragma("unroll")                                                       \
      for (int ni = 0; ni < 4; ++ni) {                                        \
        const int ba = (q + 16 * ni) * 36 + 4 * ((h16 + 4 * ks + hrd) & 7);   \
        const bf16x8 b = *(const bf16x8*)&sB[CUR][ba];                        \
        ac0[ni] = __builtin_amdgcn_mfma_f32_16x16x32_bf16(a0, b, ac0[ni], 0, 0, 0); \
        ac1[ni] = __builtin_amdgcn_mfma_f32_16x16x32_bf16(a1, b, ac1[ni], 0, 0, 0); \
      }                                                                       \
    }                                                                         \
    if ((KT) + 1 < NT) { DN_PACK(1 - (CUR), SN) __syncthreads(); }            \
  }

  for (int m0 = c0; m0 < n_e; m0 += 384) {
    const int p0g = off + min(m0 + w * 32 + q, n_e - 1);
    const int p1g = off + min(m0 + w * 32 + 16 + q, n_e - 1);
    const size_t b0 = (size_t)(p0g >> 4) * 45056 + (p0g & 15) * 8;
    const size_t b1 = (size_t)(p1g >> 4) * 45056 + (p1g & 15) * 8;

    f32x4 ac0[4], ac1[4];
#pragma unroll
    for (int ni = 0; ni < 4; ++ni) {
      ac0[ni] = (f32x4){0.f, 0.f, 0.f, 0.f};
      ac1[ni] = (f32x4){0.f, 0.f, 0.f, 0.f};
    }

    float2 s0[8], s1[8];
    DN_LDSET(s0, 0)
    DN_LDSET(s1, 1)
    DN_PACK(0, s0)
    __syncthreads();

    for (int kt = 0; kt < NT; kt += 2) {
      DN_TILE(kt, 0, s0, s1)
      DN_TILE(kt + 1, 1, s1, s0)
    }

#define DN_EPI(MI, ACV)                                                       \
  _Pragma("unroll")                                                           \
  for (int j = 0; j < 4; ++j) {                                               \
    const int er = m0 + w * 32 + (MI) * 16 + h16 * 4 + j;                     \
    if (er < n_e) {                                                           \
      _Pragma("unroll")                                                       \
      for (int ni = 0; ni < 4; ++ni)                                          \
        yp[(size_t)(off + er) * cH + nb + ni * 16 + q] = ACV[ni][j];          \
    }                                                                         \
  }
    DN_EPI(0, ac0)
    DN_EPI(1, ac1)

    if (m0 + 384 < n_e) __syncthreads();   // protect sB reuse across m-iters
  }
#undef DN_LDSET
#undef DN_PACK
#undef DN_TILE
#undef DN_EPI
}

// --------------------------------------------------------------- combine ----
__global__ __launch_bounds__(256) void combine_kernel(
    const float* __restrict__ yp, const int* __restrict__ pair_pos,
    const float* __restrict__ topk_w, float* __restrict__ out) {
  const int t = blockIdx.x;
  const int cb = threadIdx.x * 4;
  float4 s = make_float4(0.f, 0.f, 0.f, 0.f);
#pragma unroll
  for (int j = 0; j < 4; ++j) {
    const int pos = pair_pos[t * 4 + j];
    const float wj = topk_w[t * 4 + j];
    const float4 v = *(const float4*)(yp + (size_t)pos * cH + cb);
    s.x += wj * v.x; s.y += wj * v.y; s.z += wj * v.z; s.w += wj * v.w;
  }
  *(float4*)(out + (size_t)t * cH + cb) = s;
}

// ---------------------------------------------------------------- launch ----
extern "C" void kernel_launch(void* const* d_in, const int* in_sizes, int n_in,
                              void* d_out, int out_size, void* d_ws,
                              size_t ws_size, hipStream_t stream) {
  (void)in_sizes; (void)n_in; (void)out_size; (void)ws_size;
  const float* x = (const float*)d_in[0];
  const float* Wg = (const float*)d_in[1];
  const float* gw = (const float*)d_in[2];
  const float* uw = (const float*)d_in[3];
  const float* dw = (const float*)d_in[4];
  float* out = (float*)d_out;

  char* ws = (char*)d_ws;
  int* counts     = (int*)(ws + 0);          // 16
  int* cursor     = (int*)(ws + 64);         // 16
  int* offsets    = (int*)(ws + 128);        // 17
  int* topk_id    = (int*)(ws + 256);        // 4096
  float* topk_w   = (float*)(ws + 256 + 16384);
  int* pair_token = (int*)(ws + 256 + 32768);
  int* pair_pos   = (int*)(ws + 256 + 49152);
  unsigned short* actT = (unsigned short*)(ws + 65792);          // 23.07 MB
  unsigned short* xb   = (unsigned short*)(ws + 65792 + (size_t)4096 * 2816 * 2);
  float* yp = (float*)(ws + 65792 + (size_t)4096 * 2816 * 2 + (size_t)cT * cH * 2);

  hipMemsetAsync(ws, 0, 128, stream);        // counts + cursor

  xcast_kernel<<<cT * cH / (256 * 8), 256, 0, stream>>>(x, xb);
  router_kernel<<<cT, 64, 0, stream>>>(x, Wg, topk_id, topk_w, counts);
  scan_kernel<<<1, 1, 0, stream>>>(counts, offsets);
  scatter_kernel<<<cT * cK / 256, 256, 0, stream>>>(topk_id, offsets, cursor,
                                                    pair_token, pair_pos);
  gateup_kernel<<<dim3(44 * 3, cE), 256, 0, stream>>>(xb, gw, uw, offsets,
                                                      pair_token, actT);
  down_kernel<<<dim3(16 * 3, cE), 256, 0, stream>>>(actT, dw, offsets, yp);
  combine_kernel<<<cT, 256, 0, stream>>>(yp, pair_pos, topk_w, out);
}